// Round 2
// baseline (1636.046 us; speedup 1.0000x reference)
//
#include <hip/hip_runtime.h>
#include <hip/hip_bf16.h>

// Mamba2 forward, MI355X (gfx950).
// GEMM1(fp32->bf16 MFMA, bf16 out) -> conv+silu -> dt/dA -> scan(in-place y)
// -> gate+RMSNorm (bf16, aliased into z-region) -> GEMM2.
// Workspace: zxbcdt bf16 (71.8MB) + xbc fp32 (75.5MB) + dt/dA (2MB) = 149.4MB.

typedef __attribute__((ext_vector_type(8))) short bf16x8;   // 8 bf16 = 4 VGPRs
typedef __attribute__((ext_vector_type(4))) float f32x4;

static constexpr int B_ = 4;
static constexpr int L_ = 2048;
static constexpr int NROWS = B_ * L_;        // 8192 tokens
static constexpr int DMODEL = 1024;
static constexpr int DINNER = 2048;
static constexpr int NH = 32;
static constexpr int DSTATE = 128;
static constexpr int CONVDIM = DINNER + 2 * DSTATE;          // 2304
static constexpr int DINPROJ = 2 * DINNER + 2 * DSTATE + NH; // 4384

__device__ __forceinline__ unsigned pk_bf16(float a, float b) {
  unsigned ua = __builtin_bit_cast(unsigned, a);
  unsigned ub = __builtin_bit_cast(unsigned, b);
  ua = (ua + 0x7FFFu + ((ua >> 16) & 1u)) >> 16;   // RNE
  ub = (ub + 0x7FFFu + ((ub >> 16) & 1u)) >> 16;
  return (ua & 0xFFFFu) | (ub << 16);
}
__device__ __forceinline__ unsigned short bf16_of(float a) {
  unsigned ua = __builtin_bit_cast(unsigned, a);
  return (unsigned short)((ua + 0x7FFFu + ((ua >> 16) & 1u)) >> 16);
}
__device__ __forceinline__ float f_of_bf16(unsigned short s) {
  return __builtin_bit_cast(float, (unsigned)s << 16);
}

// C[M][N] = A[M][K] * Bw[N][K]^T. 128x128 tile, 256 thr = 4 waves (2x2 of 64x64),
// BK=32, MFMA 16x16x32 bf16. fp32 sources are converted to bf16 during staging.
template <bool A_F32, bool B_F32, bool C_BF16>
__global__ __launch_bounds__(256) void gemm_bt_kernel(const void* __restrict__ Ap,
                                                      const void* __restrict__ Bp,
                                                      void* __restrict__ Cp,
                                                      int M, int N, int K,
                                                      int lda, int ldb, int ldc) {
  // row stride 40 shorts (80B): 16B-aligned, conflict-free ds_read_b128.
  __shared__ unsigned short sA[128 * 40];
  __shared__ unsigned short sB[128 * 40];
  const int tid = threadIdx.x;
  const int m0 = blockIdx.y * 128;
  const int n0 = blockIdx.x * 128;
  const int w = tid >> 6;
  const int lane = tid & 63;
  const int wm = (w >> 1) * 64;
  const int wn = (w & 1) * 64;

  f32x4 acc[4][4];
#pragma unroll
  for (int i = 0; i < 4; ++i)
#pragma unroll
    for (int j = 0; j < 4; ++j) acc[i][j] = f32x4{0.f, 0.f, 0.f, 0.f};

  for (int k0 = 0; k0 < K; k0 += 32) {
#pragma unroll
    for (int s = 0; s < 2; ++s) {
      int ch = tid + s * 256;
      int row = ch >> 2;
      int c8 = (ch & 3) * 8;
      uint4 va, vb;
      if constexpr (A_F32) {
        const float* Af = (const float*)Ap + (size_t)(m0 + row) * lda + k0 + c8;
        float4 f0 = *(const float4*)Af;
        float4 f1 = *(const float4*)(Af + 4);
        va = make_uint4(pk_bf16(f0.x, f0.y), pk_bf16(f0.z, f0.w),
                        pk_bf16(f1.x, f1.y), pk_bf16(f1.z, f1.w));
      } else {
        va = *(const uint4*)((const unsigned short*)Ap + (size_t)(m0 + row) * lda + k0 + c8);
      }
      int brow = n0 + row;
      if (brow < N) {
        if constexpr (B_F32) {
          const float* Bf = (const float*)Bp + (size_t)brow * ldb + k0 + c8;
          float4 f0 = *(const float4*)Bf;
          float4 f1 = *(const float4*)(Bf + 4);
          vb = make_uint4(pk_bf16(f0.x, f0.y), pk_bf16(f0.z, f0.w),
                          pk_bf16(f1.x, f1.y), pk_bf16(f1.z, f1.w));
        } else {
          vb = *(const uint4*)((const unsigned short*)Bp + (size_t)brow * ldb + k0 + c8);
        }
      } else {
        vb = make_uint4(0u, 0u, 0u, 0u);
      }
      *(uint4*)(sA + row * 40 + c8) = va;
      *(uint4*)(sB + row * 40 + c8) = vb;
    }
    __syncthreads();
    const int k8 = (lane >> 4) * 8;  // quad*8
    const int r15 = lane & 15;
    bf16x8 af[4], bfr[4];
#pragma unroll
    for (int i = 0; i < 4; ++i)
      af[i] = *(const bf16x8*)(sA + (wm + i * 16 + r15) * 40 + k8);
#pragma unroll
    for (int j = 0; j < 4; ++j)
      bfr[j] = *(const bf16x8*)(sB + (wn + j * 16 + r15) * 40 + k8);
#pragma unroll
    for (int i = 0; i < 4; ++i)
#pragma unroll
      for (int j = 0; j < 4; ++j)
        acc[i][j] = __builtin_amdgcn_mfma_f32_16x16x32_bf16(af[i], bfr[j], acc[i][j], 0, 0, 0);
    __syncthreads();
  }

  // C/D layout: row = (lane>>4)*4 + r, col = lane&15
  const int rr = (lane >> 4) * 4;
  const int cc = lane & 15;
#pragma unroll
  for (int i = 0; i < 4; ++i) {
#pragma unroll
    for (int j = 0; j < 4; ++j) {
      int gcol = n0 + wn + j * 16 + cc;
      if (gcol < N) {
#pragma unroll
        for (int r = 0; r < 4; ++r) {
          size_t grow = (size_t)(m0 + wm + i * 16 + rr + r);
          if constexpr (C_BF16)
            ((unsigned short*)Cp)[grow * ldc + gcol] = bf16_of(acc[i][j][r]);
          else
            ((float*)Cp)[grow * ldc + gcol] = acc[i][j][r];
        }
      }
    }
  }
}

// Depthwise causal conv (D_CONV=4) + bias + SiLU over channels [2048,4352) of zxbcdt.
__global__ __launch_bounds__(256) void conv_kernel(const unsigned short* __restrict__ zx,
                                                   const float* __restrict__ conv_w,
                                                   const float* __restrict__ conv_b,
                                                   float* __restrict__ xbc) {
  int c = blockIdx.x * 256 + threadIdx.x;   // 9*256 == 2304 == CONVDIM exactly
  int row = blockIdx.y;                     // b*L + l
  int l = row & (L_ - 1);
  float acc = conv_b[c];
#pragma unroll
  for (int k = 0; k < 4; ++k) {
    int ll = l + k - 3;
    if (ll >= 0)
      acc = fmaf(f_of_bf16(zx[(size_t)(row + k - 3) * DINPROJ + DINNER + c]),
                 conv_w[c * 4 + k], acc);
  }
  acc = acc / (1.f + __expf(-acc));  // SiLU
  xbc[(size_t)row * CONVDIM + c] = acc;
}

// dt = softplus(raw + dt_bias); dA = exp(dt * (-exp(A_log)))
__global__ __launch_bounds__(256) void dt_kernel(const unsigned short* __restrict__ zx,
                                                 const float* __restrict__ dt_bias,
                                                 const float* __restrict__ A_log,
                                                 float* __restrict__ dtv,
                                                 float* __restrict__ dAv) {
  int i = blockIdx.x * 256 + threadIdx.x;
  int hh = i & (NH - 1);
  int row = i >> 5;
  float x = f_of_bf16(zx[(size_t)row * DINPROJ + DINNER + CONVDIM + hh]) + dt_bias[hh];
  float sp = (x > 20.f) ? x : log1pf(__expf(x));
  float A = -__expf(A_log[hh]);
  dtv[i] = sp;
  dAv[i] = __expf(sp * A);
}

// Selective scan, one block per (b,h): 128 blocks x 256 threads (4 waves).
// Wave w owns states n in [w*32, w*32+32), lane = p (headdim). hst[32] regs.
// Chunk T=16 staged in LDS; epilogue reduces 4 waves, adds D*x, and writes
// y IN PLACE over the x-region of xbc (block-private columns; x was staged
// into LDS before overwrite). No atomics, no extra y buffer.
__global__ __launch_bounds__(256) void scan_kernel(float* __restrict__ xbc,
                                                   const float* __restrict__ dtv,
                                                   const float* __restrict__ dAv,
                                                   const float* __restrict__ Dvec) {
  const int bid = blockIdx.x;  // b*32 + h
  const int h = bid & 31;
  const int b = bid >> 5;
  const int tid = threadIdx.x;
  const int w = tid >> 6;
  const int p = tid & 63;

  __shared__ float sX[16][64];
  __shared__ float sB[16][128];
  __shared__ float sC[16][128];
  __shared__ float sdt[16];
  __shared__ float sdA[16];
  __shared__ float sY[16][4][64];

  float hst[32];
#pragma unroll
  for (int j = 0; j < 32; ++j) hst[j] = 0.f;
  const float Dh = Dvec[h];
  const int rowbase = b * L_;

  for (int t0 = 0; t0 < L_; t0 += 16) {
    for (int e = tid; e < 1024; e += 256) {
      int tl = e >> 6, pp = e & 63;
      sX[tl][pp] = xbc[(size_t)(rowbase + t0 + tl) * CONVDIM + h * 64 + pp];
    }
    for (int e = tid; e < 2048; e += 256) {
      int tl = e >> 7, nn = e & 127;
      size_t roff = (size_t)(rowbase + t0 + tl) * CONVDIM + DINNER;
      sB[tl][nn] = xbc[roff + nn];
      sC[tl][nn] = xbc[roff + DSTATE + nn];
    }
    if (tid < 16) {
      int row = rowbase + t0 + tid;
      sdt[tid] = dtv[row * NH + h];
      sdA[tid] = dAv[row * NH + h];
    }
    __syncthreads();

    for (int tl = 0; tl < 16; ++tl) {
      float a = sdA[tl];
      float dtx = sdt[tl] * sX[tl][p];
      const float4* b4 = (const float4*)(&sB[tl][w * 32]);  // wave-uniform -> broadcast
      const float4* c4 = (const float4*)(&sC[tl][w * 32]);
      float y0 = 0.f, y1 = 0.f, y2 = 0.f, y3 = 0.f;
#pragma unroll
      for (int jj = 0; jj < 8; ++jj) {
        float4 bb = b4[jj];
        float4 cc = c4[jj];
        int j0 = jj * 4;
        hst[j0 + 0] = fmaf(hst[j0 + 0], a, dtx * bb.x); y0 = fmaf(hst[j0 + 0], cc.x, y0);
        hst[j0 + 1] = fmaf(hst[j0 + 1], a, dtx * bb.y); y1 = fmaf(hst[j0 + 1], cc.y, y1);
        hst[j0 + 2] = fmaf(hst[j0 + 2], a, dtx * bb.z); y2 = fmaf(hst[j0 + 2], cc.z, y2);
        hst[j0 + 3] = fmaf(hst[j0 + 3], a, dtx * bb.w); y3 = fmaf(hst[j0 + 3], cc.w, y3);
      }
      sY[tl][w][p] = (y0 + y1) + (y2 + y3);
    }
    __syncthreads();

    for (int e = tid; e < 1024; e += 256) {
      int tl = e >> 6, pp = e & 63;
      float v = sY[tl][0][pp] + sY[tl][1][pp] + sY[tl][2][pp] + sY[tl][3][pp]
                + Dh * sX[tl][pp];
      xbc[(size_t)(rowbase + t0 + tl) * CONVDIM + h * 64 + pp] = v;  // y over x
    }
    __syncthreads();  // protect sX/sB/sC/sY before next chunk's staging
  }
}

// yv = y * silu(z); RMSNorm over 2048; write bf16 into the (dead) z-region of
// zxbcdt, which becomes GEMM2's A with lda=DINPROJ. Per-row alias is safe:
// all z reads happen before the __syncthreads, writes after.
__global__ __launch_bounds__(256) void norm_kernel(const float* __restrict__ y_in,
                                                   unsigned short* __restrict__ zxb,
                                                   const float* __restrict__ norm_w) {
  const int row = blockIdx.x;
  const int tid = threadIdx.x;
  float v[8];
  float ss = 0.f;
#pragma unroll
  for (int i = 0; i < 8; ++i) {
    int c = tid + i * 256;
    float yv = y_in[(size_t)row * CONVDIM + c];
    float z = f_of_bf16(zxb[(size_t)row * DINPROJ + c]);
    yv *= z / (1.f + __expf(-z));
    v[i] = yv;
    ss = fmaf(yv, yv, ss);
  }
#pragma unroll
  for (int o = 32; o > 0; o >>= 1) ss += __shfl_down(ss, o, 64);
  __shared__ float sred[4];
  if ((tid & 63) == 0) sred[tid >> 6] = ss;
  __syncthreads();
  float tot = (sred[0] + sred[1]) + (sred[2] + sred[3]);
  float r = rsqrtf(tot * (1.f / (float)DINNER) + 1e-5f);
#pragma unroll
  for (int i = 0; i < 8; ++i) {
    int c = tid + i * 256;
    zxb[(size_t)row * DINPROJ + c] = bf16_of(v[i] * r * norm_w[c]);
  }
}

extern "C" void kernel_launch(void* const* d_in, const int* in_sizes, int n_in,
                              void* d_out, int out_size, void* d_ws, size_t ws_size,
                              hipStream_t stream) {
  (void)in_sizes; (void)n_in; (void)out_size;
  const float* u          = (const float*)d_in[0];   // query
  const float* in_proj_w  = (const float*)d_in[3];
  const float* conv_w     = (const float*)d_in[4];
  const float* conv_b     = (const float*)d_in[5];
  const float* dt_bias    = (const float*)d_in[6];
  const float* A_log      = (const float*)d_in[7];
  const float* Dvec       = (const float*)d_in[8];
  const float* norm_w     = (const float*)d_in[9];
  const float* out_proj_w = (const float*)d_in[10];
  float* out = (float*)d_out;

  // Workspace layout (all 256B aligned):
  constexpr size_t SZ_ZX  = (size_t)NROWS * DINPROJ * 2;  // 71,827,456
  constexpr size_t SZ_XBC = (size_t)NROWS * CONVDIM * 4;  // 75,497,472
  constexpr size_t SZ_DT  = (size_t)NROWS * NH * 4;       //  1,048,576
  constexpr size_t NEED = SZ_ZX + SZ_XBC + 2 * SZ_DT;     // 149,422,080
  if (ws_size < NEED) return;  // diagnosable: leaves d_out poisoned -> absmax = max|ref|

  char* p = (char*)d_ws;
  unsigned short* zxb = (unsigned short*)p; p += SZ_ZX;
  float* xbc = (float*)p;                   p += SZ_XBC;
  float* dtv = (float*)p;                   p += SZ_DT;
  float* dAv = (float*)p;                   p += SZ_DT;

  // zxbcdt[8192][4384] = u @ in_proj_w^T   (fp32 in, bf16 out)
  gemm_bt_kernel<true, true, true><<<dim3(35, 64), 256, 0, stream>>>(
      u, in_proj_w, zxb, NROWS, DINPROJ, DMODEL, DMODEL, DMODEL, DINPROJ);
  conv_kernel<<<dim3(9, NROWS), 256, 0, stream>>>(zxb, conv_w, conv_b, xbc);
  dt_kernel<<<(NROWS * NH) / 256, 256, 0, stream>>>(zxb, dt_bias, A_log, dtv, dAv);
  scan_kernel<<<128, 256, 0, stream>>>(xbc, dtv, dAv, Dvec);
  norm_kernel<<<NROWS, 256, 0, stream>>>(xbc, zxb, norm_w);
  // out[8192][1024] = ynorm @ out_proj_w^T   (A bf16 lda=4384, B fp32, C fp32)
  gemm_bt_kernel<false, true, false><<<dim3(8, 64), 256, 0, stream>>>(
      zxb, out_proj_w, out, NROWS, DMODEL, DINNER, DINPROJ, DINNER, DMODEL);
}

// Round 3
// 802.369 us; speedup vs baseline: 2.0390x; 2.0390x over previous
//
#include <hip/hip_runtime.h>
#include <hip/hip_bf16.h>

// Mamba2 forward, MI355X (gfx950).
// GEMM1(fp32->bf16 MFMA, bf16 out) -> conv+silu -> dt -> chunked-SSD scan (MFMA)
// -> gate+RMSNorm (bf16, aliased into z-region) -> GEMM2.

typedef __attribute__((ext_vector_type(8))) short bf16x8;   // 8 bf16 = 4 VGPRs
typedef __attribute__((ext_vector_type(4))) float f32x4;

static constexpr int B_ = 4;
static constexpr int L_ = 2048;
static constexpr int NROWS = B_ * L_;        // 8192 tokens
static constexpr int DMODEL = 1024;
static constexpr int DINNER = 2048;
static constexpr int NH = 32;
static constexpr int DSTATE = 128;
static constexpr int CONVDIM = DINNER + 2 * DSTATE;          // 2304
static constexpr int DINPROJ = 2 * DINNER + 2 * DSTATE + NH; // 4384
static constexpr int Q_ = 64;                 // SSD chunk length
static constexpr int NCHUNK = L_ / Q_;        // 32

__device__ __forceinline__ unsigned pk_bf16(float a, float b) {
  unsigned ua = __builtin_bit_cast(unsigned, a);
  unsigned ub = __builtin_bit_cast(unsigned, b);
  ua = (ua + 0x7FFFu + ((ua >> 16) & 1u)) >> 16;   // RNE
  ub = (ub + 0x7FFFu + ((ub >> 16) & 1u)) >> 16;
  return (ua & 0xFFFFu) | (ub << 16);
}
__device__ __forceinline__ unsigned short bf16_of(float a) {
  unsigned ua = __builtin_bit_cast(unsigned, a);
  return (unsigned short)((ua + 0x7FFFu + ((ua >> 16) & 1u)) >> 16);
}
__device__ __forceinline__ float f_of_bf16(unsigned short s) {
  return __builtin_bit_cast(float, (unsigned)s << 16);
}

// ---------------- GEMM (unchanged from R2) ----------------
template <bool A_F32, bool B_F32, bool C_BF16>
__global__ __launch_bounds__(256) void gemm_bt_kernel(const void* __restrict__ Ap,
                                                      const void* __restrict__ Bp,
                                                      void* __restrict__ Cp,
                                                      int M, int N, int K,
                                                      int lda, int ldb, int ldc) {
  __shared__ unsigned short sA[128 * 40];
  __shared__ unsigned short sB[128 * 40];
  const int tid = threadIdx.x;
  const int m0 = blockIdx.y * 128;
  const int n0 = blockIdx.x * 128;
  const int w = tid >> 6;
  const int lane = tid & 63;
  const int wm = (w >> 1) * 64;
  const int wn = (w & 1) * 64;

  f32x4 acc[4][4];
#pragma unroll
  for (int i = 0; i < 4; ++i)
#pragma unroll
    for (int j = 0; j < 4; ++j) acc[i][j] = f32x4{0.f, 0.f, 0.f, 0.f};

  for (int k0 = 0; k0 < K; k0 += 32) {
#pragma unroll
    for (int s = 0; s < 2; ++s) {
      int ch = tid + s * 256;
      int row = ch >> 2;
      int c8 = (ch & 3) * 8;
      uint4 va, vb;
      if constexpr (A_F32) {
        const float* Af = (const float*)Ap + (size_t)(m0 + row) * lda + k0 + c8;
        float4 f0 = *(const float4*)Af;
        float4 f1 = *(const float4*)(Af + 4);
        va = make_uint4(pk_bf16(f0.x, f0.y), pk_bf16(f0.z, f0.w),
                        pk_bf16(f1.x, f1.y), pk_bf16(f1.z, f1.w));
      } else {
        va = *(const uint4*)((const unsigned short*)Ap + (size_t)(m0 + row) * lda + k0 + c8);
      }
      int brow = n0 + row;
      if (brow < N) {
        if constexpr (B_F32) {
          const float* Bf = (const float*)Bp + (size_t)brow * ldb + k0 + c8;
          float4 f0 = *(const float4*)Bf;
          float4 f1 = *(const float4*)(Bf + 4);
          vb = make_uint4(pk_bf16(f0.x, f0.y), pk_bf16(f0.z, f0.w),
                          pk_bf16(f1.x, f1.y), pk_bf16(f1.z, f1.w));
        } else {
          vb = *(const uint4*)((const unsigned short*)Bp + (size_t)brow * ldb + k0 + c8);
        }
      } else {
        vb = make_uint4(0u, 0u, 0u, 0u);
      }
      *(uint4*)(sA + row * 40 + c8) = va;
      *(uint4*)(sB + row * 40 + c8) = vb;
    }
    __syncthreads();
    const int k8 = (lane >> 4) * 8;
    const int r15 = lane & 15;
    bf16x8 af[4], bfr[4];
#pragma unroll
    for (int i = 0; i < 4; ++i)
      af[i] = *(const bf16x8*)(sA + (wm + i * 16 + r15) * 40 + k8);
#pragma unroll
    for (int j = 0; j < 4; ++j)
      bfr[j] = *(const bf16x8*)(sB + (wn + j * 16 + r15) * 40 + k8);
#pragma unroll
    for (int i = 0; i < 4; ++i)
#pragma unroll
      for (int j = 0; j < 4; ++j)
        acc[i][j] = __builtin_amdgcn_mfma_f32_16x16x32_bf16(af[i], bfr[j], acc[i][j], 0, 0, 0);
    __syncthreads();
  }

  const int rr = (lane >> 4) * 4;
  const int cc = lane & 15;
#pragma unroll
  for (int i = 0; i < 4; ++i) {
#pragma unroll
    for (int j = 0; j < 4; ++j) {
      int gcol = n0 + wn + j * 16 + cc;
      if (gcol < N) {
#pragma unroll
        for (int r = 0; r < 4; ++r) {
          size_t grow = (size_t)(m0 + wm + i * 16 + rr + r);
          if constexpr (C_BF16)
            ((unsigned short*)Cp)[grow * ldc + gcol] = bf16_of(acc[i][j][r]);
          else
            ((float*)Cp)[grow * ldc + gcol] = acc[i][j][r];
        }
      }
    }
  }
}

// ---------------- conv + SiLU (unchanged) ----------------
__global__ __launch_bounds__(256) void conv_kernel(const unsigned short* __restrict__ zx,
                                                   const float* __restrict__ conv_w,
                                                   const float* __restrict__ conv_b,
                                                   float* __restrict__ xbc) {
  int c = blockIdx.x * 256 + threadIdx.x;
  int row = blockIdx.y;
  int l = row & (L_ - 1);
  float acc = conv_b[c];
#pragma unroll
  for (int k = 0; k < 4; ++k) {
    int ll = l + k - 3;
    if (ll >= 0)
      acc = fmaf(f_of_bf16(zx[(size_t)(row + k - 3) * DINPROJ + DINNER + c]),
                 conv_w[c * 4 + k], acc);
  }
  acc = acc / (1.f + __expf(-acc));
  xbc[(size_t)row * CONVDIM + c] = acc;
}

// dt = softplus(raw + dt_bias)
__global__ __launch_bounds__(256) void dt_kernel(const unsigned short* __restrict__ zx,
                                                 const float* __restrict__ dt_bias,
                                                 float* __restrict__ dtv) {
  int i = blockIdx.x * 256 + threadIdx.x;
  int hh = i & (NH - 1);
  int row = i >> 5;
  float x = f_of_bf16(zx[(size_t)row * DINPROJ + DINNER + CONVDIM + hh]) + dt_bias[hh];
  dtv[i] = (x > 20.f) ? x : log1pf(__expf(x));
}

// ---------------- chunked-SSD scan ----------------
// One block per (b,h): 128 blocks x 256 threads (4 waves). Chunk Q=64.
// Per chunk: S = C@B^T -> S~ (causal decay mask) -> Y = rowscale(C@h_prev^T) + S~@X^T
// h = exp(A*cs_last)*h + X^T @ (B^T * g)   (h fp32 in registers as MFMA C operand)
// Y (+ D*x) written in place over the x-region of xbc.
__global__ __launch_bounds__(256) void scan_ssd_kernel(float* __restrict__ xbc,
                                                       const float* __restrict__ dtv,
                                                       const float* __restrict__ A_log,
                                                       const float* __restrict__ Dvec) {
  const int bid = blockIdx.x;  // b*32 + h
  const int h = bid & 31;
  const int b = bid >> 5;
  const int tid = threadIdx.x;
  const int w = tid >> 6;
  const int lane = tid & 63;
  const int quad = lane >> 4;
  const int c15 = lane & 15;

  // LDS carve (63,488 B): sXt[64][72] | sBq[64][136] (S~[64][72] alias)
  //                       sCB: Cq[64][136] / BtT[128][72] | sH[64][136] | 4x64 fp32
  __shared__ char smem[63488];
  unsigned short* sXt = (unsigned short*)smem;                    // X^T  [p][t]
  unsigned short* sBq = (unsigned short*)(smem + 9216);           // B    [s][n]
  unsigned short* sCB = (unsigned short*)(smem + 26624);          // C[t][n] / BtT[n][s]
  unsigned short* sH  = (unsigned short*)(smem + 45056);          // h    [p][n]
  float* sdt = (float*)(smem + 62464);
  float* scs = sdt + 64;
  float* sg  = sdt + 128;
  float* srt = sdt + 192;

  const float A = -__expf(A_log[h]);
  const float Dh = Dvec[h];
  const int rowbase = b * L_;

  f32x4 hacc[2][4];
#pragma unroll
  for (int i = 0; i < 2; ++i)
#pragma unroll
    for (int j = 0; j < 4; ++j) hacc[i][j] = f32x4{0.f, 0.f, 0.f, 0.f};

  const int wt = w >> 1;   // t-half for S/Y phases
  const int wx = w & 1;    // s-half (S) / p-half (Y)

  for (int c = 0; c < NCHUNK; ++c) {
    const int r0 = rowbase + c * Q_;

    // P1: wave 0 computes dt chunk + inclusive cumsum + decay factors.
    if (w == 0) {
      float v = dtv[(size_t)(r0 + lane) * NH + h];
      sdt[lane] = v;
      float s = v;
#pragma unroll
      for (int off = 1; off < 64; off <<= 1) {
        float t = __shfl_up(s, off, 64);
        if (lane >= off) s += t;
      }
      scs[lane] = s;
      float cl = __shfl(s, 63, 64);
      sg[lane] = __expf(A * (cl - s)) * v;     // for state update
      srt[lane] = __expf(A * s);               // row factor / d_last at lane 63
    }
    __syncthreads();  // B1

    // P2: stage Xt (transpose), Bq, Cq, and h_prev -> sH.
    for (int e = tid; e < 512; e += 256) {     // Xt: lane varies t -> LDS conflict-free
      int t = e & 63, pb = e >> 6;
      const float* src = &xbc[(size_t)(r0 + t) * CONVDIM + h * 64 + pb * 8];
      float4 f0 = ((const float4*)src)[0];
      float4 f1 = ((const float4*)src)[1];
      float arr[8] = {f0.x, f0.y, f0.z, f0.w, f1.x, f1.y, f1.z, f1.w};
#pragma unroll
      for (int j = 0; j < 8; ++j) sXt[(pb * 8 + j) * 72 + t] = bf16_of(arr[j]);
    }
    for (int e = tid; e < 2048; e += 256) {    // Bq, Cq coalesced
      int s = e >> 5, nq = e & 31;
      size_t off = (size_t)(r0 + s) * CONVDIM + DINNER;
      float4 fb = *(const float4*)&xbc[off + nq * 4];
      float4 fc = *(const float4*)&xbc[off + DSTATE + nq * 4];
      unsigned* db = (unsigned*)&sBq[s * 136 + nq * 4];
      db[0] = pk_bf16(fb.x, fb.y); db[1] = pk_bf16(fb.z, fb.w);
      unsigned* dc = (unsigned*)&sCB[s * 136 + nq * 4];
      dc[0] = pk_bf16(fc.x, fc.y); dc[1] = pk_bf16(fc.z, fc.w);
    }
    {  // h_prev (bf16) for the C@h MFMA; wave owns p in [wp*32,+32), n in [wn*64,+64)
      int wp = w >> 1, wn = w & 1;
#pragma unroll
      for (int i = 0; i < 2; ++i)
#pragma unroll
        for (int j = 0; j < 4; ++j)
#pragma unroll
          for (int r = 0; r < 4; ++r)
            sH[(wp * 32 + i * 16 + quad * 4 + r) * 136 + wn * 64 + j * 16 + c15] =
                bf16_of(hacc[i][j][r]);
    }
    __syncthreads();  // B2
    const float dlast = srt[63];  // read before B6 (next-chunk P1 races only past B6)

    // MFMA1: S = Cq @ Bq^T  (K = n = 128)
    f32x4 sacc[2][2];
#pragma unroll
    for (int i = 0; i < 2; ++i)
#pragma unroll
      for (int j = 0; j < 2; ++j) sacc[i][j] = f32x4{0.f, 0.f, 0.f, 0.f};
#pragma unroll
    for (int kk = 0; kk < 4; ++kk) {
      int k8 = quad * 8 + kk * 32;
      bf16x8 a0 = *(const bf16x8*)&sCB[(wt * 32 + c15) * 136 + k8];
      bf16x8 a1 = *(const bf16x8*)&sCB[(wt * 32 + 16 + c15) * 136 + k8];
      bf16x8 b0 = *(const bf16x8*)&sBq[(wx * 32 + c15) * 136 + k8];
      bf16x8 b1 = *(const bf16x8*)&sBq[(wx * 32 + 16 + c15) * 136 + k8];
      sacc[0][0] = __builtin_amdgcn_mfma_f32_16x16x32_bf16(a0, b0, sacc[0][0], 0, 0, 0);
      sacc[0][1] = __builtin_amdgcn_mfma_f32_16x16x32_bf16(a0, b1, sacc[0][1], 0, 0, 0);
      sacc[1][0] = __builtin_amdgcn_mfma_f32_16x16x32_bf16(a1, b0, sacc[1][0], 0, 0, 0);
      sacc[1][1] = __builtin_amdgcn_mfma_f32_16x16x32_bf16(a1, b1, sacc[1][1], 0, 0, 0);
    }
    __syncthreads();  // B3 (Bq now dead -> S~ alias)

    // S~ = causal-mask(S) * exp(A*(cs_t - cs_s)) * dt_s, bf16 into Bq area (stride 72)
    unsigned short* sS = sBq;
#pragma unroll
    for (int i = 0; i < 2; ++i)
#pragma unroll
      for (int j = 0; j < 2; ++j) {
        int scol = wx * 32 + j * 16 + c15;
        float css = scs[scol];
        float dts = sdt[scol];
#pragma unroll
        for (int r = 0; r < 4; ++r) {
          int trow = wt * 32 + i * 16 + quad * 4 + r;
          float v = 0.f;
          if (scol <= trow) v = sacc[i][j][r] * __expf(A * (scs[trow] - css)) * dts;
          sS[trow * 72 + scol] = bf16_of(v);
        }
      }
    __syncthreads();  // B4

    // Y: first C@h_prev (K = n), then per-row scale by srt[t], then += S~@Xt (K = s).
    f32x4 yacc[2][2];
#pragma unroll
    for (int i = 0; i < 2; ++i)
#pragma unroll
      for (int j = 0; j < 2; ++j) yacc[i][j] = f32x4{0.f, 0.f, 0.f, 0.f};
#pragma unroll
    for (int kk = 0; kk < 4; ++kk) {  // K = n = 128
      int k8 = quad * 8 + kk * 32;
      bf16x8 a0 = *(const bf16x8*)&sCB[(wt * 32 + c15) * 136 + k8];
      bf16x8 a1 = *(const bf16x8*)&sCB[(wt * 32 + 16 + c15) * 136 + k8];
      bf16x8 b0 = *(const bf16x8*)&sH[(wx * 32 + c15) * 136 + k8];
      bf16x8 b1 = *(const bf16x8*)&sH[(wx * 32 + 16 + c15) * 136 + k8];
      yacc[0][0] = __builtin_amdgcn_mfma_f32_16x16x32_bf16(a0, b0, yacc[0][0], 0, 0, 0);
      yacc[0][1] = __builtin_amdgcn_mfma_f32_16x16x32_bf16(a0, b1, yacc[0][1], 0, 0, 0);
      yacc[1][0] = __builtin_amdgcn_mfma_f32_16x16x32_bf16(a1, b0, yacc[1][0], 0, 0, 0);
      yacc[1][1] = __builtin_amdgcn_mfma_f32_16x16x32_bf16(a1, b1, yacc[1][1], 0, 0, 0);
    }
#pragma unroll
    for (int i = 0; i < 2; ++i)
#pragma unroll
      for (int r = 0; r < 4; ++r) {
        float rt = srt[wt * 32 + i * 16 + quad * 4 + r];
        yacc[i][0][r] *= rt;
        yacc[i][1][r] *= rt;
      }
#pragma unroll
    for (int kk = 0; kk < 2; ++kk) {  // K = s = 64
      int k8 = quad * 8 + kk * 32;
      bf16x8 a0 = *(const bf16x8*)&sS[(wt * 32 + c15) * 72 + k8];
      bf16x8 a1 = *(const bf16x8*)&sS[(wt * 32 + 16 + c15) * 72 + k8];
      bf16x8 b0 = *(const bf16x8*)&sXt[(wx * 32 + c15) * 72 + k8];
      bf16x8 b1 = *(const bf16x8*)&sXt[(wx * 32 + 16 + c15) * 72 + k8];
      yacc[0][0] = __builtin_amdgcn_mfma_f32_16x16x32_bf16(a0, b0, yacc[0][0], 0, 0, 0);
      yacc[0][1] = __builtin_amdgcn_mfma_f32_16x16x32_bf16(a0, b1, yacc[0][1], 0, 0, 0);
      yacc[1][0] = __builtin_amdgcn_mfma_f32_16x16x32_bf16(a1, b0, yacc[1][0], 0, 0, 0);
      yacc[1][1] = __builtin_amdgcn_mfma_f32_16x16x32_bf16(a1, b1, yacc[1][1], 0, 0, 0);
    }
    __syncthreads();  // B5 (Cq + S~ dead -> BtT alias into sCB)

    // Stage BtT[n][s] = B[s][n] * g_s (lane varies s -> conflict-free stores)
    unsigned short* sBtT = sCB;
    for (int e = tid; e < 1024; e += 256) {
      int s = e & 63, nb = e >> 6;
      const float* src = &xbc[(size_t)(r0 + s) * CONVDIM + DINNER + nb * 8];
      float4 f0 = ((const float4*)src)[0];
      float4 f1 = ((const float4*)src)[1];
      float g = sg[s];
      float arr[8] = {f0.x, f0.y, f0.z, f0.w, f1.x, f1.y, f1.z, f1.w};
#pragma unroll
      for (int j = 0; j < 8; ++j) sBtT[(nb * 8 + j) * 72 + s] = bf16_of(arr[j] * g);
    }
    __syncthreads();  // B6

    // h = dlast*h + Xt @ BtT^T  (K = s = 64; fp32 h as MFMA C operand)
    {
      int wp = w >> 1, wn = w & 1;
#pragma unroll
      for (int i = 0; i < 2; ++i)
#pragma unroll
        for (int j = 0; j < 4; ++j)
#pragma unroll
          for (int r = 0; r < 4; ++r) hacc[i][j][r] *= dlast;
#pragma unroll
      for (int kk = 0; kk < 2; ++kk) {
        int k8 = quad * 8 + kk * 32;
        bf16x8 a0 = *(const bf16x8*)&sXt[(wp * 32 + c15) * 72 + k8];
        bf16x8 a1 = *(const bf16x8*)&sXt[(wp * 32 + 16 + c15) * 72 + k8];
        bf16x8 bfr[4];
#pragma unroll
        for (int j = 0; j < 4; ++j)
          bfr[j] = *(const bf16x8*)&sBtT[(wn * 64 + j * 16 + c15) * 72 + k8];
#pragma unroll
        for (int j = 0; j < 4; ++j) {
          hacc[0][j] = __builtin_amdgcn_mfma_f32_16x16x32_bf16(a0, bfr[j], hacc[0][j], 0, 0, 0);
          hacc[1][j] = __builtin_amdgcn_mfma_f32_16x16x32_bf16(a1, bfr[j], hacc[1][j], 0, 0, 0);
        }
      }
    }

    // Y write (+ D*x) in place over the x-region (block-private columns).
#pragma unroll
    for (int i = 0; i < 2; ++i)
#pragma unroll
      for (int j = 0; j < 2; ++j) {
        int p = wx * 32 + j * 16 + c15;
#pragma unroll
        for (int r = 0; r < 4; ++r) {
          int t = wt * 32 + i * 16 + quad * 4 + r;
          float xv = f_of_bf16(sXt[p * 72 + t]);
          xbc[(size_t)(r0 + t) * CONVDIM + h * 64 + p] = yacc[i][j][r] + Dh * xv;
        }
      }
    // loop-back: next P1 only writes sdt/scs/sg/srt (not read here); B1 protects rest.
  }
}

// ---------------- gate + RMSNorm (unchanged) ----------------
__global__ __launch_bounds__(256) void norm_kernel(const float* __restrict__ y_in,
                                                   unsigned short* __restrict__ zxb,
                                                   const float* __restrict__ norm_w) {
  const int row = blockIdx.x;
  const int tid = threadIdx.x;
  float v[8];
  float ss = 0.f;
#pragma unroll
  for (int i = 0; i < 8; ++i) {
    int c = tid + i * 256;
    float yv = y_in[(size_t)row * CONVDIM + c];
    float z = f_of_bf16(zxb[(size_t)row * DINPROJ + c]);
    yv *= z / (1.f + __expf(-z));
    v[i] = yv;
    ss = fmaf(yv, yv, ss);
  }
#pragma unroll
  for (int o = 32; o > 0; o >>= 1) ss += __shfl_down(ss, o, 64);
  __shared__ float sred[4];
  if ((tid & 63) == 0) sred[tid >> 6] = ss;
  __syncthreads();
  float tot = (sred[0] + sred[1]) + (sred[2] + sred[3]);
  float r = rsqrtf(tot * (1.f / (float)DINNER) + 1e-5f);
#pragma unroll
  for (int i = 0; i < 8; ++i) {
    int c = tid + i * 256;
    zxb[(size_t)row * DINPROJ + c] = bf16_of(v[i] * r * norm_w[c]);
  }
}

extern "C" void kernel_launch(void* const* d_in, const int* in_sizes, int n_in,
                              void* d_out, int out_size, void* d_ws, size_t ws_size,
                              hipStream_t stream) {
  (void)in_sizes; (void)n_in; (void)out_size;
  const float* u          = (const float*)d_in[0];
  const float* in_proj_w  = (const float*)d_in[3];
  const float* conv_w     = (const float*)d_in[4];
  const float* conv_b     = (const float*)d_in[5];
  const float* dt_bias    = (const float*)d_in[6];
  const float* A_log      = (const float*)d_in[7];
  const float* Dvec       = (const float*)d_in[8];
  const float* norm_w     = (const float*)d_in[9];
  const float* out_proj_w = (const float*)d_in[10];
  float* out = (float*)d_out;

  constexpr size_t SZ_ZX  = (size_t)NROWS * DINPROJ * 2;
  constexpr size_t SZ_XBC = (size_t)NROWS * CONVDIM * 4;
  constexpr size_t SZ_DT  = (size_t)NROWS * NH * 4;
  constexpr size_t NEED = SZ_ZX + SZ_XBC + SZ_DT;  // 148.4 MB
  if (ws_size < NEED) return;

  char* p = (char*)d_ws;
  unsigned short* zxb = (unsigned short*)p; p += SZ_ZX;
  float* xbc = (float*)p;                   p += SZ_XBC;
  float* dtv = (float*)p;                   p += SZ_DT;

  gemm_bt_kernel<true, true, true><<<dim3(35, 64), 256, 0, stream>>>(
      u, in_proj_w, zxb, NROWS, DINPROJ, DMODEL, DMODEL, DMODEL, DINPROJ);
  conv_kernel<<<dim3(9, NROWS), 256, 0, stream>>>(zxb, conv_w, conv_b, xbc);
  dt_kernel<<<(NROWS * NH) / 256, 256, 0, stream>>>(zxb, dt_bias, dtv);
  scan_ssd_kernel<<<128, 256, 0, stream>>>(xbc, dtv, A_log, Dvec);
  norm_kernel<<<NROWS, 256, 0, stream>>>(xbc, zxb, norm_w);
  gemm_bt_kernel<false, true, false><<<dim3(8, 64), 256, 0, stream>>>(
      zxb, out_proj_w, out, NROWS, DMODEL, DINNER, DINPROJ, DINNER, DMODEL);
}

// Round 4
// 520.524 us; speedup vs baseline: 3.1431x; 1.5415x over previous
//
#include <hip/hip_runtime.h>
#include <hip/hip_bf16.h>

// Mamba2 forward, MI355X (gfx950).
// casts -> GEMM1 (global_load_lds MFMA, bf16 out) -> conv+silu (bf16) -> dt
// -> SSD pass A (local Y + chunk states, parallel over chunks)
// -> SSD pass B (sequential chunk-state scan, tiny)
// -> SSD pass C (inter-chunk Y, parallel) -> gate+RMSNorm -> GEMM2.
// States (67MB bf16) live in d_out scratch (33.5MB) + ws region shared with
// the cast buffers (dead after GEMM1). ws NEED = 148.37MB (<= proven 149.4MB).

typedef __attribute__((ext_vector_type(8))) short bf16x8;
typedef __attribute__((ext_vector_type(4))) float f32x4;

static constexpr int B_ = 4;
static constexpr int L_ = 2048;
static constexpr int NROWS = B_ * L_;
static constexpr int DMODEL = 1024;
static constexpr int DINNER = 2048;
static constexpr int NH = 32;
static constexpr int DSTATE = 128;
static constexpr int CONVDIM = DINNER + 2 * DSTATE;          // 2304
static constexpr int DINPROJ = 2 * DINNER + 2 * DSTATE + NH; // 4384
static constexpr int Q_ = 64;
static constexpr int NCHUNK = L_ / Q_;                        // 32

__device__ __forceinline__ unsigned pk_bf16(float a, float b) {
  unsigned ua = __builtin_bit_cast(unsigned, a);
  unsigned ub = __builtin_bit_cast(unsigned, b);
  ua = (ua + 0x7FFFu + ((ua >> 16) & 1u)) >> 16;
  ub = (ub + 0x7FFFu + ((ub >> 16) & 1u)) >> 16;
  return (ua & 0xFFFFu) | (ub << 16);
}
__device__ __forceinline__ unsigned short bf16_of(float a) {
  unsigned ua = __builtin_bit_cast(unsigned, a);
  return (unsigned short)((ua + 0x7FFFu + ((ua >> 16) & 1u)) >> 16);
}
__device__ __forceinline__ float f_of_bf16(unsigned short s) {
  return __builtin_bit_cast(float, (unsigned)s << 16);
}
__device__ __forceinline__ unsigned short* state_slot(unsigned short* lo,
                                                      unsigned short* hi,
                                                      int bh, int c) {
  int i = bh * NCHUNK + c;
  return (i < 2048) ? lo + (size_t)i * 8192 : hi + (size_t)(i - 2048) * 8192;
}

// fp32 -> bf16, 4 elems/thread, n divisible by 1024.
__global__ __launch_bounds__(256) void cast4_kernel(const float* __restrict__ in,
                                                    unsigned short* __restrict__ out) {
  int i = blockIdx.x * 256 + threadIdx.x;
  float4 v = ((const float4*)in)[i];
  ((uint2*)out)[i] = make_uint2(pk_bf16(v.x, v.y), pk_bf16(v.z, v.w));
}

// C[M][N] = A[M][K] * Bw[N][K]^T, bf16 in, m97-style global_load_lds staging.
// 128x128 tile, 256 thr (4 waves, 2x2 of 64x64), BK=32, unpadded LDS [128][32].
template <bool C_BF16>
__global__ __launch_bounds__(256) void gemm_lds_kernel(
    const unsigned short* __restrict__ A, const unsigned short* __restrict__ Bw,
    void* __restrict__ Cp, int M, int N, int K, int lda, int ldb, int ldc) {
  __shared__ unsigned short sA[128 * 32];
  __shared__ unsigned short sB[128 * 32];
  const int tid = threadIdx.x;
  const int w = tid >> 6;
  const int lane = tid & 63;
  const int m0 = blockIdx.y * 128;
  const int n0 = blockIdx.x * 128;
  const int wm = (w >> 1) * 64;
  const int wn = (w & 1) * 64;
  const int lr = lane >> 2;          // 16 rows per issue, 4 lanes/row
  const int lc8 = (lane & 3) * 8;    // 8 bf16 = 16B per lane

  f32x4 acc[4][4];
#pragma unroll
  for (int i = 0; i < 4; ++i)
#pragma unroll
    for (int j = 0; j < 4; ++j) acc[i][j] = f32x4{0.f, 0.f, 0.f, 0.f};

  auto ldsA = (__attribute__((address_space(3))) unsigned short*)sA;
  auto ldsB = (__attribute__((address_space(3))) unsigned short*)sB;

  for (int k0 = 0; k0 < K; k0 += 32) {
#pragma unroll
    for (int s = 0; s < 2; ++s) {
      int row = w * 32 + s * 16;  // wave-uniform LDS base; lane scatters +lane*16B
      __builtin_amdgcn_global_load_lds(
          (const __attribute__((address_space(1))) void*)(A + (size_t)(m0 + row + lr) * lda + k0 + lc8),
          (__attribute__((address_space(3))) void*)(ldsA + row * 32), 16, 0, 0);
      __builtin_amdgcn_global_load_lds(
          (const __attribute__((address_space(1))) void*)(Bw + (size_t)(n0 + row + lr) * ldb + k0 + lc8),
          (__attribute__((address_space(3))) void*)(ldsB + row * 32), 16, 0, 0);
    }
    __syncthreads();
    const int k8 = (lane >> 4) * 8;
    const int r15 = lane & 15;
    bf16x8 af[4], bfr[4];
#pragma unroll
    for (int i = 0; i < 4; ++i)
      af[i] = *(const bf16x8*)(sA + (wm + i * 16 + r15) * 32 + k8);
#pragma unroll
    for (int j = 0; j < 4; ++j)
      bfr[j] = *(const bf16x8*)(sB + (wn + j * 16 + r15) * 32 + k8);
#pragma unroll
    for (int i = 0; i < 4; ++i)
#pragma unroll
      for (int j = 0; j < 4; ++j)
        acc[i][j] = __builtin_amdgcn_mfma_f32_16x16x32_bf16(af[i], bfr[j], acc[i][j], 0, 0, 0);
    __syncthreads();
  }

  const int rr = (lane >> 4) * 4;
  const int cc = lane & 15;
#pragma unroll
  for (int i = 0; i < 4; ++i) {
#pragma unroll
    for (int j = 0; j < 4; ++j) {
      int gcol = n0 + wn + j * 16 + cc;
      if (gcol < N) {
#pragma unroll
        for (int r = 0; r < 4; ++r) {
          size_t grow = (size_t)(m0 + wm + i * 16 + rr + r);
          if constexpr (C_BF16)
            ((unsigned short*)Cp)[grow * ldc + gcol] = bf16_of(acc[i][j][r]);
          else
            ((float*)Cp)[grow * ldc + gcol] = acc[i][j][r];
        }
      }
    }
  }
}

// conv(D_CONV=4) + bias + SiLU; bf16 in (zxb cols [2048,4352)), bf16 out.
__global__ __launch_bounds__(256) void conv_kernel(const unsigned short* __restrict__ zx,
                                                   const float* __restrict__ conv_w,
                                                   const float* __restrict__ conv_b,
                                                   unsigned short* __restrict__ xbc) {
  int c = blockIdx.x * 256 + threadIdx.x;  // 9*256 == CONVDIM
  int row = blockIdx.y;
  int l = row & (L_ - 1);
  float acc = conv_b[c];
#pragma unroll
  for (int k = 0; k < 4; ++k) {
    int ll = l + k - 3;
    if (ll >= 0)
      acc = fmaf(f_of_bf16(zx[(size_t)(row + k - 3) * DINPROJ + DINNER + c]),
                 conv_w[c * 4 + k], acc);
  }
  acc = acc / (1.f + __expf(-acc));
  xbc[(size_t)row * CONVDIM + c] = bf16_of(acc);
}

__global__ __launch_bounds__(256) void dt_kernel(const unsigned short* __restrict__ zx,
                                                 const float* __restrict__ dt_bias,
                                                 float* __restrict__ dtv) {
  int i = blockIdx.x * 256 + threadIdx.x;
  int hh = i & (NH - 1);
  int row = i >> 5;
  float x = f_of_bf16(zx[(size_t)row * DINPROJ + DINNER + CONVDIM + hh]) + dt_bias[hh];
  dtv[i] = (x > 20.f) ? x : log1pf(__expf(x));
}

// ---- SSD pass A: per (b,chunk,head) block. Local Y (+D*x) in place over the
// x-region of xbc; chunk state S_c -> state slot (bf16 [p][n], 64x128).
__global__ __launch_bounds__(256) void ssd_passA(unsigned short* __restrict__ xbc,
                                                 const float* __restrict__ dtv,
                                                 const float* __restrict__ A_log,
                                                 const float* __restrict__ Dvec,
                                                 unsigned short* __restrict__ st_lo,
                                                 unsigned short* __restrict__ st_hi) {
  const int bid = blockIdx.x;          // ((b*32 + c)*32 + h)
  const int h = bid & 31;
  const int c = (bid >> 5) & 31;
  const int b = bid >> 10;
  const int bh = b * 32 + h;
  const int tid = threadIdx.x;
  const int w = tid >> 6;
  const int lane = tid & 63;
  const int quad = lane >> 4;
  const int c15 = lane & 15;

  __shared__ unsigned short sXt[64 * 72];   // X^T [p][t]
  __shared__ unsigned short sBq[64 * 136];  // B [s][n] stride 136; S~ alias stride 72
  __shared__ unsigned short sCB[128 * 72];  // C [t][n] stride 136 / BtT [n][s] stride 72
  __shared__ float sdt[64], scs[64], sg[64];

  const float A = -__expf(A_log[h]);
  const float Dh = Dvec[h];
  const int r0 = b * L_ + c * Q_;

  if (w == 0) {
    float v = dtv[(size_t)(r0 + lane) * NH + h];
    sdt[lane] = v;
    float s = v;
#pragma unroll
    for (int off = 1; off < 64; off <<= 1) {
      float t = __shfl_up(s, off, 64);
      if (lane >= off) s += t;
    }
    scs[lane] = s;
    float T = __shfl(s, 63, 64);
    sg[lane] = __expf(A * (T - s)) * v;
  }
  for (int e = tid; e < 512; e += 256) {   // Xt transpose (conflict-free b16 writes)
    int t = e & 63, pb = e >> 6;
    uint4 v = *(const uint4*)&xbc[(size_t)(r0 + t) * CONVDIM + h * 64 + pb * 8];
    const unsigned short* sv = (const unsigned short*)&v;
#pragma unroll
    for (int j = 0; j < 8; ++j) sXt[(pb * 8 + j) * 72 + t] = sv[j];
  }
  for (int e = tid; e < 1024; e += 256) {  // B, C coalesced dwordx4
    int s = e >> 4, ch = e & 15;
    size_t roff = (size_t)(r0 + s) * CONVDIM + DINNER;
    *(uint4*)&sBq[s * 136 + ch * 8] = *(const uint4*)&xbc[roff + ch * 8];
    *(uint4*)&sCB[s * 136 + ch * 8] = *(const uint4*)&xbc[roff + DSTATE + ch * 8];
  }
  __syncthreads();  // B1

  const int wt = w >> 1, wx = w & 1;
  // S = C @ B^T (K=128)
  f32x4 sacc[2][2];
#pragma unroll
  for (int i = 0; i < 2; ++i)
#pragma unroll
    for (int j = 0; j < 2; ++j) sacc[i][j] = f32x4{0.f, 0.f, 0.f, 0.f};
#pragma unroll
  for (int kk = 0; kk < 4; ++kk) {
    int k8 = quad * 8 + kk * 32;
    bf16x8 a0 = *(const bf16x8*)&sCB[(wt * 32 + c15) * 136 + k8];
    bf16x8 a1 = *(const bf16x8*)&sCB[(wt * 32 + 16 + c15) * 136 + k8];
    bf16x8 b0 = *(const bf16x8*)&sBq[(wx * 32 + c15) * 136 + k8];
    bf16x8 b1 = *(const bf16x8*)&sBq[(wx * 32 + 16 + c15) * 136 + k8];
    sacc[0][0] = __builtin_amdgcn_mfma_f32_16x16x32_bf16(a0, b0, sacc[0][0], 0, 0, 0);
    sacc[0][1] = __builtin_amdgcn_mfma_f32_16x16x32_bf16(a0, b1, sacc[0][1], 0, 0, 0);
    sacc[1][0] = __builtin_amdgcn_mfma_f32_16x16x32_bf16(a1, b0, sacc[1][0], 0, 0, 0);
    sacc[1][1] = __builtin_amdgcn_mfma_f32_16x16x32_bf16(a1, b1, sacc[1][1], 0, 0, 0);
  }
  __syncthreads();  // B2

  // S~ into sBq (stride 72); BtT[n][s] = B[s][n]*g_s into sCB (stride 72, global re-read)
#pragma unroll
  for (int i = 0; i < 2; ++i)
#pragma unroll
    for (int j = 0; j < 2; ++j) {
      int scol = wx * 32 + j * 16 + c15;
      float css = scs[scol], dts = sdt[scol];
#pragma unroll
      for (int r = 0; r < 4; ++r) {
        int trow = wt * 32 + i * 16 + quad * 4 + r;
        float v = (scol <= trow) ? sacc[i][j][r] * __expf(A * (scs[trow] - css)) * dts : 0.f;
        sBq[trow * 72 + scol] = bf16_of(v);
      }
    }
  for (int e = tid; e < 1024; e += 256) {
    int s = e & 63, nb = e >> 6;
    uint4 v = *(const uint4*)&xbc[(size_t)(r0 + s) * CONVDIM + DINNER + nb * 8];
    float g = sg[s];
    const unsigned short* sv = (const unsigned short*)&v;
#pragma unroll
    for (int j = 0; j < 8; ++j)
      sCB[(nb * 8 + j) * 72 + s] = bf16_of(f_of_bf16(sv[j]) * g);
  }
  __syncthreads();  // B3

  // Y_local = S~ @ Xt (K=64), += D*x, bf16 in place over x
  f32x4 yacc[2][2];
#pragma unroll
  for (int i = 0; i < 2; ++i)
#pragma unroll
    for (int j = 0; j < 2; ++j) yacc[i][j] = f32x4{0.f, 0.f, 0.f, 0.f};
#pragma unroll
  for (int kk = 0; kk < 2; ++kk) {
    int k8 = quad * 8 + kk * 32;
    bf16x8 a0 = *(const bf16x8*)&sBq[(wt * 32 + c15) * 72 + k8];
    bf16x8 a1 = *(const bf16x8*)&sBq[(wt * 32 + 16 + c15) * 72 + k8];
    bf16x8 b0 = *(const bf16x8*)&sXt[(wx * 32 + c15) * 72 + k8];
    bf16x8 b1 = *(const bf16x8*)&sXt[(wx * 32 + 16 + c15) * 72 + k8];
    yacc[0][0] = __builtin_amdgcn_mfma_f32_16x16x32_bf16(a0, b0, yacc[0][0], 0, 0, 0);
    yacc[0][1] = __builtin_amdgcn_mfma_f32_16x16x32_bf16(a0, b1, yacc[0][1], 0, 0, 0);
    yacc[1][0] = __builtin_amdgcn_mfma_f32_16x16x32_bf16(a1, b0, yacc[1][0], 0, 0, 0);
    yacc[1][1] = __builtin_amdgcn_mfma_f32_16x16x32_bf16(a1, b1, yacc[1][1], 0, 0, 0);
  }
#pragma unroll
  for (int i = 0; i < 2; ++i)
#pragma unroll
    for (int j = 0; j < 2; ++j) {
      int p = wx * 32 + j * 16 + c15;
#pragma unroll
      for (int r = 0; r < 4; ++r) {
        int t = wt * 32 + i * 16 + quad * 4 + r;
        float xv = f_of_bf16(sXt[p * 72 + t]);
        xbc[(size_t)(r0 + t) * CONVDIM + h * 64 + p] = bf16_of(yacc[i][j][r] + Dh * xv);
      }
    }

  // S_c = Xt @ BtT^T (K=64) -> state slot
  f32x4 hacc[2][4];
#pragma unroll
  for (int i = 0; i < 2; ++i)
#pragma unroll
    for (int j = 0; j < 4; ++j) hacc[i][j] = f32x4{0.f, 0.f, 0.f, 0.f};
  const int wp = w >> 1, wn = w & 1;
#pragma unroll
  for (int kk = 0; kk < 2; ++kk) {
    int k8 = quad * 8 + kk * 32;
    bf16x8 a0 = *(const bf16x8*)&sXt[(wp * 32 + c15) * 72 + k8];
    bf16x8 a1 = *(const bf16x8*)&sXt[(wp * 32 + 16 + c15) * 72 + k8];
    bf16x8 bfr[4];
#pragma unroll
    for (int j = 0; j < 4; ++j)
      bfr[j] = *(const bf16x8*)&sCB[(wn * 64 + j * 16 + c15) * 72 + k8];
#pragma unroll
    for (int j = 0; j < 4; ++j) {
      hacc[0][j] = __builtin_amdgcn_mfma_f32_16x16x32_bf16(a0, bfr[j], hacc[0][j], 0, 0, 0);
      hacc[1][j] = __builtin_amdgcn_mfma_f32_16x16x32_bf16(a1, bfr[j], hacc[1][j], 0, 0, 0);
    }
  }
  unsigned short* slot = state_slot(st_lo, st_hi, bh, c);
#pragma unroll
  for (int i = 0; i < 2; ++i)
#pragma unroll
    for (int j = 0; j < 4; ++j)
#pragma unroll
      for (int r = 0; r < 4; ++r) {
        int p = wp * 32 + i * 16 + quad * 4 + r;
        int n = wn * 64 + j * 16 + c15;
        slot[p * 128 + n] = bf16_of(hacc[i][j][r]);
      }
}

// ---- SSD pass B: h_c = d_c*h_{c-1} + S_c; slot overwritten with h_{c-1}.
// grid 256 = (bh, p-half); thread owns 16 contiguous elems.
__global__ __launch_bounds__(256) void ssd_passB(const float* __restrict__ dtv,
                                                 const float* __restrict__ A_log,
                                                 unsigned short* __restrict__ st_lo,
                                                 unsigned short* __restrict__ st_hi) {
  const int bh = blockIdx.x >> 1;
  const int ph = blockIdx.x & 1;
  const int h = bh & 31;
  const int b = bh >> 5;
  const int tid = threadIdx.x;
  __shared__ float sd[NCHUNK];
  const float A = -__expf(A_log[h]);
  if (tid < NCHUNK) {
    float s = 0.f;
    const float* dp = dtv + (size_t)(b * L_ + tid * Q_) * NH + h;
    for (int i = 0; i < Q_; ++i) s += dp[(size_t)i * NH];
    sd[tid] = __expf(A * s);
  }
  __syncthreads();
  float hreg[16];
#pragma unroll
  for (int k = 0; k < 16; ++k) hreg[k] = 0.f;
  const size_t eoff = (size_t)ph * 4096 + (size_t)tid * 16;
  for (int c = 0; c < NCHUNK; ++c) {
    unsigned short* sp = state_slot(st_lo, st_hi, bh, c) + eoff;
    uint4 t0 = ((const uint4*)sp)[0];
    uint4 t1 = ((const uint4*)sp)[1];
    unsigned o[8];
#pragma unroll
    for (int k = 0; k < 8; ++k) o[k] = pk_bf16(hreg[2 * k], hreg[2 * k + 1]);
    ((uint4*)sp)[0] = make_uint4(o[0], o[1], o[2], o[3]);
    ((uint4*)sp)[1] = make_uint4(o[4], o[5], o[6], o[7]);
    float d = sd[c];
    const unsigned short* tv0 = (const unsigned short*)&t0;
    const unsigned short* tv1 = (const unsigned short*)&t1;
#pragma unroll
    for (int k = 0; k < 8; ++k) hreg[k] = d * hreg[k] + f_of_bf16(tv0[k]);
#pragma unroll
    for (int k = 0; k < 8; ++k) hreg[8 + k] = d * hreg[8 + k] + f_of_bf16(tv1[k]);
  }
}

// ---- SSD pass C: Y += exp(A*cs_t) * (C @ h_prev^T); RMW on xbc x-region.
__global__ __launch_bounds__(256) void ssd_passC(unsigned short* __restrict__ xbc,
                                                 const float* __restrict__ dtv,
                                                 const float* __restrict__ A_log,
                                                 const unsigned short* __restrict__ st_lo,
                                                 const unsigned short* __restrict__ st_hi) {
  const int bid = blockIdx.x;
  const int h = bid & 31;
  const int c = (bid >> 5) & 31;
  const int b = bid >> 10;
  const int bh = b * 32 + h;
  const int tid = threadIdx.x;
  const int w = tid >> 6;
  const int lane = tid & 63;
  const int quad = lane >> 4;
  const int c15 = lane & 15;

  __shared__ unsigned short sC[64 * 136];
  __shared__ unsigned short sH[64 * 136];
  __shared__ float srt[64];

  const float A = -__expf(A_log[h]);
  const int r0 = b * L_ + c * Q_;

  if (w == 0) {
    float v = dtv[(size_t)(r0 + lane) * NH + h];
    float s = v;
#pragma unroll
    for (int off = 1; off < 64; off <<= 1) {
      float t = __shfl_up(s, off, 64);
      if (lane >= off) s += t;
    }
    srt[lane] = __expf(A * s);
  }
  const unsigned short* slot =
      state_slot((unsigned short*)st_lo, (unsigned short*)st_hi, bh, c);
  for (int e = tid; e < 1024; e += 256) {
    int s = e >> 4, ch = e & 15;
    *(uint4*)&sC[s * 136 + ch * 8] =
        *(const uint4*)&xbc[(size_t)(r0 + s) * CONVDIM + DINNER + DSTATE + ch * 8];
    *(uint4*)&sH[s * 136 + ch * 8] = *(const uint4*)&slot[s * 128 + ch * 8];
  }
  __syncthreads();

  const int wt = w >> 1, wx = w & 1;
  f32x4 yacc[2][2];
#pragma unroll
  for (int i = 0; i < 2; ++i)
#pragma unroll
    for (int j = 0; j < 2; ++j) yacc[i][j] = f32x4{0.f, 0.f, 0.f, 0.f};
#pragma unroll
  for (int kk = 0; kk < 4; ++kk) {
    int k8 = quad * 8 + kk * 32;
    bf16x8 a0 = *(const bf16x8*)&sC[(wt * 32 + c15) * 136 + k8];
    bf16x8 a1 = *(const bf16x8*)&sC[(wt * 32 + 16 + c15) * 136 + k8];
    bf16x8 b0 = *(const bf16x8*)&sH[(wx * 32 + c15) * 136 + k8];
    bf16x8 b1 = *(const bf16x8*)&sH[(wx * 32 + 16 + c15) * 136 + k8];
    yacc[0][0] = __builtin_amdgcn_mfma_f32_16x16x32_bf16(a0, b0, yacc[0][0], 0, 0, 0);
    yacc[0][1] = __builtin_amdgcn_mfma_f32_16x16x32_bf16(a0, b1, yacc[0][1], 0, 0, 0);
    yacc[1][0] = __builtin_amdgcn_mfma_f32_16x16x32_bf16(a1, b0, yacc[1][0], 0, 0, 0);
    yacc[1][1] = __builtin_amdgcn_mfma_f32_16x16x32_bf16(a1, b1, yacc[1][1], 0, 0, 0);
  }
#pragma unroll
  for (int i = 0; i < 2; ++i)
#pragma unroll
    for (int j = 0; j < 2; ++j) {
      int p = wx * 32 + j * 16 + c15;
#pragma unroll
      for (int r = 0; r < 4; ++r) {
        int t = wt * 32 + i * 16 + quad * 4 + r;
        size_t ga = (size_t)(r0 + t) * CONVDIM + h * 64 + p;
        float v = yacc[i][j][r] * srt[t] + f_of_bf16(xbc[ga]);
        xbc[ga] = bf16_of(v);
      }
    }
}

// gate + RMSNorm; y bf16 from xbc, z bf16 from zxb; out bf16 into z-region.
__global__ __launch_bounds__(256) void norm_kernel(const unsigned short* __restrict__ y_in,
                                                   unsigned short* __restrict__ zxb,
                                                   const float* __restrict__ norm_w) {
  const int row = blockIdx.x;
  const int tid = threadIdx.x;
  float v[8];
  float ss = 0.f;
#pragma unroll
  for (int i = 0; i < 8; ++i) {
    int c = tid + i * 256;
    float yv = f_of_bf16(y_in[(size_t)row * CONVDIM + c]);
    float z = f_of_bf16(zxb[(size_t)row * DINPROJ + c]);
    yv *= z / (1.f + __expf(-z));
    v[i] = yv;
    ss = fmaf(yv, yv, ss);
  }
#pragma unroll
  for (int o = 32; o > 0; o >>= 1) ss += __shfl_down(ss, o, 64);
  __shared__ float sred[4];
  if ((tid & 63) == 0) sred[tid >> 6] = ss;
  __syncthreads();
  float tot = (sred[0] + sred[1]) + (sred[2] + sred[3]);
  float r = rsqrtf(tot * (1.f / (float)DINNER) + 1e-5f);
#pragma unroll
  for (int i = 0; i < 8; ++i) {
    int c = tid + i * 256;
    zxb[(size_t)row * DINPROJ + c] = bf16_of(v[i] * r * norm_w[c]);
  }
}

extern "C" void kernel_launch(void* const* d_in, const int* in_sizes, int n_in,
                              void* d_out, int out_size, void* d_ws, size_t ws_size,
                              hipStream_t stream) {
  (void)in_sizes; (void)n_in; (void)out_size;
  const float* u          = (const float*)d_in[0];
  const float* in_proj_w  = (const float*)d_in[3];
  const float* conv_w     = (const float*)d_in[4];
  const float* conv_b     = (const float*)d_in[5];
  const float* dt_bias    = (const float*)d_in[6];
  const float* A_log      = (const float*)d_in[7];
  const float* Dvec       = (const float*)d_in[8];
  const float* norm_w     = (const float*)d_in[9];
  const float* out_proj_w = (const float*)d_in[10];
  float* out = (float*)d_out;

  constexpr size_t SZ_ZX   = (size_t)NROWS * DINPROJ * 2;   // 71,827,456
  constexpr size_t SZ_XBC  = (size_t)NROWS * CONVDIM * 2;   // 37,748,736
  constexpr size_t SZ_DT   = (size_t)NROWS * NH * 4;        //  1,048,576
  constexpr size_t SZ_SHR  = 33554432;                      // casts, later states-hi
  constexpr size_t SZ_WOUT = (size_t)DMODEL * DINNER * 2;   //  4,194,304
  constexpr size_t NEED = SZ_ZX + SZ_XBC + SZ_DT + SZ_SHR + SZ_WOUT;  // 148,373,504
  if (ws_size < NEED) return;

  char* p = (char*)d_ws;
  unsigned short* zxb  = (unsigned short*)p; p += SZ_ZX;
  unsigned short* xbc  = (unsigned short*)p; p += SZ_XBC;
  float* dtv           = (float*)p;          p += SZ_DT;
  char* shared_reg     = p;                  p += SZ_SHR;
  unsigned short* wout_bf = (unsigned short*)p;

  unsigned short* u_bf   = (unsigned short*)shared_reg;                 // 16.8MB
  unsigned short* win_bf = (unsigned short*)(shared_reg + 16777216);    //  9.0MB
  unsigned short* st_lo  = (unsigned short*)d_out;                      // 2048 slots
  unsigned short* st_hi  = (unsigned short*)shared_reg;                 // 2048 slots

  cast4_kernel<<<(NROWS * DMODEL) / 1024, 256, 0, stream>>>(u, u_bf);
  cast4_kernel<<<(DINPROJ * DMODEL) / 1024, 256, 0, stream>>>(in_proj_w, win_bf);
  cast4_kernel<<<(DMODEL * DINNER) / 1024, 256, 0, stream>>>(out_proj_w, wout_bf);

  gemm_lds_kernel<true><<<dim3(35, 64), 256, 0, stream>>>(
      u_bf, win_bf, zxb, NROWS, DINPROJ, DMODEL, DMODEL, DMODEL, DINPROJ);
  conv_kernel<<<dim3(9, NROWS), 256, 0, stream>>>(zxb, conv_w, conv_b, xbc);
  dt_kernel<<<(NROWS * NH) / 256, 256, 0, stream>>>(zxb, dt_bias, dtv);

  ssd_passA<<<B_ * NCHUNK * NH, 256, 0, stream>>>(xbc, dtv, A_log, Dvec, st_lo, st_hi);
  ssd_passB<<<B_ * NH * 2, 256, 0, stream>>>(dtv, A_log, st_lo, st_hi);
  ssd_passC<<<B_ * NCHUNK * NH, 256, 0, stream>>>(xbc, dtv, A_log, st_lo, st_hi);

  norm_kernel<<<NROWS, 256, 0, stream>>>(xbc, zxb, norm_w);
  gemm_lds_kernel<false><<<dim3(8, 64), 256, 0, stream>>>(
      zxb, wout_bf, out, NROWS, DMODEL, DINNER, DINPROJ, DINNER, DMODEL);
}